// Round 4
// baseline (3861.423 us; speedup 1.0000x reference)
//
#include <hip/hip_runtime.h>

#define NPTS 8192
#define NP   2048
#define NB   8
#define CIN  128
#define COUT 256
#define KNN_K 16
#define GQ_TOTAL (NB * NP)          // 16384
#define GEMM_BLOCKS 512
#define GEMM_QPB (GQ_TOTAL / GEMM_BLOCKS)   // 32

typedef unsigned long long u64;

__device__ __forceinline__ float mulrn(float a, float b){ return __fmul_rn(a,b); }
__device__ __forceinline__ float addrn(float a, float b){ return __fadd_rn(a,b); }
__device__ __forceinline__ float subrn(float a, float b){ return __fsub_rn(a,b); }

__device__ __forceinline__ unsigned spread3(unsigned a){ // 4-bit -> bits 0,3,6,9
  return (a & 1u) | ((a & 2u) << 2) | ((a & 4u) << 4) | ((a & 8u) << 6);
}

// ---------------- K0: Morton counting sort (per batch) -----------------------
// Bins the 8192 points of one batch into 4096 Morton cells (4 bits/axis) so
// that consecutive sorted points are spatially coherent. Order within a cell
// is nondeterministic (atomics) but the FPS result is order-independent.
__global__ __launch_bounds__(1024) void k_sort(const float* __restrict__ xyz,
    float* __restrict__ sxb, float* __restrict__ syb, float* __restrict__ szb,
    int* __restrict__ sob) {
  const int b = blockIdx.x;
  const int tid = threadIdx.x;
  const int lane = tid & 63;
  const int wid = tid >> 6;                  // 0..15
  __shared__ unsigned hist[4096];            // 16 KB
  __shared__ float bb[16][6];
  __shared__ unsigned wsum[16];
  const float* base = xyz + (size_t)b * NPTS * 3;
  float px[8], py[8], pz[8];
  const int i0 = tid * 8;
  {
    const float4* b4 = (const float4*)(base + (size_t)i0 * 3);  // 96B/thread
    float4 v0=b4[0], v1=b4[1], v2=b4[2], v3=b4[3], v4=b4[4], v5=b4[5];
    px[0]=v0.x;py[0]=v0.y;pz[0]=v0.z; px[1]=v0.w;py[1]=v1.x;pz[1]=v1.y;
    px[2]=v1.z;py[2]=v1.w;pz[2]=v2.x; px[3]=v2.y;py[3]=v2.z;pz[3]=v2.w;
    px[4]=v3.x;py[4]=v3.y;pz[4]=v3.z; px[5]=v3.w;py[5]=v4.x;pz[5]=v4.y;
    px[6]=v4.z;py[6]=v4.w;pz[6]=v5.x; px[7]=v5.y;py[7]=v5.z;pz[7]=v5.w;
  }
  float mnx=px[0],mxx=px[0],mny=py[0],mxy=py[0],mnz=pz[0],mxz=pz[0];
#pragma unroll
  for (int j = 1; j < 8; ++j) {
    mnx=fminf(mnx,px[j]); mxx=fmaxf(mxx,px[j]);
    mny=fminf(mny,py[j]); mxy=fmaxf(mxy,py[j]);
    mnz=fminf(mnz,pz[j]); mxz=fmaxf(mxz,pz[j]);
  }
#pragma unroll
  for (int off = 1; off < 64; off <<= 1) {
    mnx=fminf(mnx,__shfl_xor(mnx,off,64)); mxx=fmaxf(mxx,__shfl_xor(mxx,off,64));
    mny=fminf(mny,__shfl_xor(mny,off,64)); mxy=fmaxf(mxy,__shfl_xor(mxy,off,64));
    mnz=fminf(mnz,__shfl_xor(mnz,off,64)); mxz=fmaxf(mxz,__shfl_xor(mxz,off,64));
  }
  if (lane == 0) {
    bb[wid][0]=mnx; bb[wid][1]=mxx; bb[wid][2]=mny;
    bb[wid][3]=mxy; bb[wid][4]=mnz; bb[wid][5]=mxz;
  }
  for (int i = tid; i < 4096; i += 1024) hist[i] = 0;
  __syncthreads();
  float gmnx=bb[0][0], gmxx=bb[0][1], gmny=bb[0][2];
  float gmxy=bb[0][3], gmnz=bb[0][4], gmxz=bb[0][5];
#pragma unroll 1
  for (int w = 1; w < 16; ++w) {
    gmnx=fminf(gmnx,bb[w][0]); gmxx=fmaxf(gmxx,bb[w][1]);
    gmny=fminf(gmny,bb[w][2]); gmxy=fmaxf(gmxy,bb[w][3]);
    gmnz=fminf(gmnz,bb[w][4]); gmxz=fmaxf(gmxz,bb[w][5]);
  }
  const float rx=gmxx-gmnx, ry=gmxy-gmny, rz=gmxz-gmnz;
  const float sx_ = (rx>0.f) ? 1023.f/rx : 0.f;
  const float sy_ = (ry>0.f) ? 1023.f/ry : 0.f;
  const float sz_ = (rz>0.f) ? 1023.f/rz : 0.f;
  int cell[8];
#pragma unroll
  for (int j = 0; j < 8; ++j) {
    int qx = (int)((px[j]-gmnx)*sx_); qx = max(0, min(1023, qx));
    int qy = (int)((py[j]-gmny)*sy_); qy = max(0, min(1023, qy));
    int qz = (int)((pz[j]-gmnz)*sz_); qz = max(0, min(1023, qz));
    cell[j] = (int)(spread3((unsigned)qx>>6) | (spread3((unsigned)qy>>6)<<1)
                  | (spread3((unsigned)qz>>6)<<2));
    atomicAdd(&hist[cell[j]], 1u);
  }
  __syncthreads();
  unsigned h0=hist[4*tid], h1=hist[4*tid+1], h2=hist[4*tid+2], h3=hist[4*tid+3];
  unsigned tsum = h0+h1+h2+h3;
  unsigned sc = tsum;
#pragma unroll
  for (int off = 1; off < 64; off <<= 1) {
    unsigned n = __shfl_up(sc, off, 64);
    if (lane >= off) sc += n;
  }
  if (lane == 63) wsum[wid] = sc;
  __syncthreads();
  unsigned wbase = 0;
#pragma unroll
  for (int w = 0; w < 16; ++w) wbase += (w < wid) ? wsum[w] : 0u;
  unsigned tb = wbase + sc - tsum;
  __syncthreads();                 // everyone has read their bins; safe to overwrite
  hist[4*tid+0] = tb;
  hist[4*tid+1] = tb + h0;
  hist[4*tid+2] = tb + h0 + h1;
  hist[4*tid+3] = tb + h0 + h1 + h2;
  __syncthreads();
  float* dx = sxb + (size_t)b * NPTS;
  float* dy = syb + (size_t)b * NPTS;
  float* dz = szb + (size_t)b * NPTS;
  int*   dorig = sob + (size_t)b * NPTS;
#pragma unroll
  for (int j = 0; j < 8; ++j) {
    unsigned dst = atomicAdd(&hist[cell[j]], 1u);
    dx[dst] = px[j]; dy[dst] = py[j]; dz[dst] = pz[j];
    dorig[dst] = i0 + j;
  }
}

// ---------------- K1: farthest point sampling with wave-level pruning --------
// 1024 threads, 8 Morton-sorted pts/thread; each wave owns 512 spatially
// compact points with a register bbox. A wave whose bbox is provably farther
// from the new centroid than its max-dist skips the update (exact: min() can't
// change). Candidate u64 = (dist_bits<<32)|((8191-orig)<<13)|sorted_pos.
__global__ __launch_bounds__(1024) void k_fps(const float* __restrict__ xyz,
    const float* __restrict__ sxb, const float* __restrict__ syb,
    const float* __restrict__ szb, const int* __restrict__ sob,
    float* __restrict__ out_xyz) {
  const int b = blockIdx.x;
  const int tid = threadIdx.x;
  const int lane = tid & 63;
  const int wid = tid >> 6;                 // 0..15
  __shared__ float s_x[NPTS], s_y[NPTS], s_z[NPTS];   // 96 KB
  __shared__ u64 s_red[2][16];
  const float* sx = sxb + (size_t)b * NPTS;
  const float* sy = syb + (size_t)b * NPTS;
  const float* sz = szb + (size_t)b * NPTS;
  const int*   so = sob + (size_t)b * NPTS;

  float px[8], py[8], pz[8], dist[8];
  unsigned lo[8];
  const int i0 = tid * 8;
  {
    const float4 a0=*(const float4*)(sx+i0), a1=*(const float4*)(sx+i0+4);
    px[0]=a0.x;px[1]=a0.y;px[2]=a0.z;px[3]=a0.w;px[4]=a1.x;px[5]=a1.y;px[6]=a1.z;px[7]=a1.w;
    const float4 b0=*(const float4*)(sy+i0), b1=*(const float4*)(sy+i0+4);
    py[0]=b0.x;py[1]=b0.y;py[2]=b0.z;py[3]=b0.w;py[4]=b1.x;py[5]=b1.y;py[6]=b1.z;py[7]=b1.w;
    const float4 c0=*(const float4*)(sz+i0), c1=*(const float4*)(sz+i0+4);
    pz[0]=c0.x;pz[1]=c0.y;pz[2]=c0.z;pz[3]=c0.w;pz[4]=c1.x;pz[5]=c1.y;pz[6]=c1.z;pz[7]=c1.w;
    const int4 o0=*(const int4*)(so+i0), o1=*(const int4*)(so+i0+4);
    lo[0]=((8191u-(unsigned)o0.x)<<13)|(unsigned)(i0+0);
    lo[1]=((8191u-(unsigned)o0.y)<<13)|(unsigned)(i0+1);
    lo[2]=((8191u-(unsigned)o0.z)<<13)|(unsigned)(i0+2);
    lo[3]=((8191u-(unsigned)o0.w)<<13)|(unsigned)(i0+3);
    lo[4]=((8191u-(unsigned)o1.x)<<13)|(unsigned)(i0+4);
    lo[5]=((8191u-(unsigned)o1.y)<<13)|(unsigned)(i0+5);
    lo[6]=((8191u-(unsigned)o1.z)<<13)|(unsigned)(i0+6);
    lo[7]=((8191u-(unsigned)o1.w)<<13)|(unsigned)(i0+7);
  }
  float wmnx=px[0],wmxx=px[0],wmny=py[0],wmxy=py[0],wmnz=pz[0],wmxz=pz[0];
#pragma unroll
  for (int j = 0; j < 8; ++j) {
    s_x[i0+j]=px[j]; s_y[i0+j]=py[j]; s_z[i0+j]=pz[j];
    dist[j] = 1e10f;
    if (j) {
      wmnx=fminf(wmnx,px[j]); wmxx=fmaxf(wmxx,px[j]);
      wmny=fminf(wmny,py[j]); wmxy=fmaxf(wmxy,py[j]);
      wmnz=fminf(wmnz,pz[j]); wmxz=fmaxf(wmxz,pz[j]);
    }
  }
#pragma unroll
  for (int off = 1; off < 64; off <<= 1) {
    wmnx=fminf(wmnx,__shfl_xor(wmnx,off,64)); wmxx=fmaxf(wmxx,__shfl_xor(wmxx,off,64));
    wmny=fminf(wmny,__shfl_xor(wmny,off,64)); wmxy=fmaxf(wmxy,__shfl_xor(wmxy,off,64));
    wmnz=fminf(wmnz,__shfl_xor(wmnz,off,64)); wmxz=fmaxf(wmxz,__shfl_xor(wmxz,off,64));
  }
  // initial centroid = ORIGINAL point 0 of this batch
  const float* obase = xyz + (size_t)b * NPTS * 3;
  float cx = obase[0], cy = obase[1], cz = obase[2];
  if (tid == 0) {
    size_t o = (size_t)b * NP * 3;
    out_xyz[o+0]=cx; out_xyz[o+1]=cy; out_xyz[o+2]=cz;
  }
  u64 wave_pk = 0ull;
  float wave_ub = 1e30f;       // forces first step active
  __syncthreads();

#pragma unroll 1
  for (int s = 1; s < NP; ++s) {
    const int p = s & 1;
    // conservative wave skip test (slack covers fp error; errs toward active)
    float ex = fmaxf(fmaxf(wmnx-cx, cx-wmxx), 0.f);
    float ey = fmaxf(fmaxf(wmny-cy, cy-wmxy), 0.f);
    float ez = fmaxf(fmaxf(wmnz-cz, cz-wmxz), 0.f);
    float dmin2 = ex*ex + ey*ey + ez*ez;
    if (!(dmin2 * 0.999998f >= wave_ub)) {
      float bv = -1.0f; unsigned blo = 0u;
#pragma unroll
      for (int j = 0; j < 8; ++j) {
        float dx = subrn(px[j], cx);
        float dy = subrn(py[j], cy);
        float dz = subrn(pz[j], cz);
        float dd = addrn(addrn(mulrn(dx,dx), mulrn(dy,dy)), mulrn(dz,dz));
        float dm = fminf(dist[j], dd);
        dist[j] = dm;
        bool g = (dm > bv) || ((dm == bv) && (lo[j] > blo));
        bv  = g ? dm    : bv;
        blo = g ? lo[j] : blo;
      }
      u64 pk = ((u64)__float_as_uint(bv) << 32) | blo;
#pragma unroll
      for (int off = 1; off < 64; off <<= 1) {
        u64 o = __shfl_xor(pk, off, 64);
        pk = (o > pk) ? o : pk;
      }
      wave_pk = pk;
      wave_ub = __uint_as_float((unsigned)(wave_pk >> 32));
    }
    if (lane == 0) s_red[p][wid] = wave_pk;
    __syncthreads();
    u64 t0=s_red[p][0],  t1=s_red[p][1],  t2=s_red[p][2],  t3=s_red[p][3];
    u64 t4=s_red[p][4],  t5=s_red[p][5],  t6=s_red[p][6],  t7=s_red[p][7];
    u64 t8=s_red[p][8],  t9=s_red[p][9],  ta=s_red[p][10], tb=s_red[p][11];
    u64 tc=s_red[p][12], td=s_red[p][13], te=s_red[p][14], tf=s_red[p][15];
    t0=(t1>t0)?t1:t0; t2=(t3>t2)?t3:t2; t4=(t5>t4)?t5:t4; t6=(t7>t6)?t7:t6;
    t8=(t9>t8)?t9:t8; ta=(tb>ta)?tb:ta; tc=(td>tc)?td:tc; te=(tf>te)?tf:te;
    t0=(t2>t0)?t2:t0; t4=(t6>t4)?t6:t4; t8=(ta>t8)?ta:t8; tc=(te>tc)?te:tc;
    t0=(t4>t0)?t4:t0; t8=(tc>t8)?tc:t8;
    t0=(t8>t0)?t8:t0;
    const int ri = (int)(t0 & 0x1fffu);
    cx = s_x[ri]; cy = s_y[ri]; cz = s_z[ri];
    if (tid == 0) {
      size_t o = ((size_t)b * NP + s) * 3;
      out_xyz[o+0]=cx; out_xyz[o+1]=cy; out_xyz[o+2]=cz;
    }
  }
}

// ---------------- K2: 16-NN per sampled point (one wave per query) -----------
__global__ __launch_bounds__(256) void k_knn(const float* __restrict__ xyz,
                                             const float* __restrict__ new_xyz,
                                             int* __restrict__ knn) {
  __shared__ float4 s_pts[NPTS];   // 128 KB
  const int gq0 = blockIdx.x * 64;
  const int b = gq0 >> 11;
  const float* base = xyz + (size_t)b * NPTS * 3;
  for (int i = threadIdx.x; i < NPTS; i += 256) {
    float x = base[i * 3 + 0], y = base[i * 3 + 1], z = base[i * 3 + 2];
    float n = addrn(addrn(mulrn(x, x), mulrn(y, y)), mulrn(z, z));
    s_pts[i] = make_float4(x, y, z, n);
  }
  __syncthreads();
  const int wave = threadIdx.x >> 6;
  const int lane = threadIdx.x & 63;
#pragma unroll 1
  for (int qi = 0; qi < 16; ++qi) {
    const int gq = gq0 + wave * 16 + qi;
    const float qx = new_xyz[(size_t)gq * 3 + 0];
    const float qy = new_xyz[(size_t)gq * 3 + 1];
    const float qz = new_xyz[(size_t)gq * 3 + 2];
    const float qn = addrn(addrn(mulrn(qx, qx), mulrn(qy, qy)), mulrn(qz, qz));
    float bd = (lane < 16) ? 1e30f : -1e30f;
    int   bi = 0;
    float r = 1e30f;
#pragma unroll 1
    for (int c0 = 0; c0 < NPTS; c0 += 64) {
      float4 p = s_pts[c0 + lane];
      float dot = addrn(addrn(mulrn(qx, p.x), mulrn(qy, p.y)), mulrn(qz, p.z));
      float dd = addrn(addrn(mulrn(-2.0f, dot), qn), p.w);
      unsigned long long m = __ballot(dd < r);
      while (m) {
        int src = __builtin_ctzll(m);
        m &= (m - 1);
        float v = __shfl(dd, src, 64);
        if (v < r) {
          int vi = c0 + src;
          float bdn = __shfl_down(bd, 1, 64);
          int   bin_ = __shfl_down(bi, 1, 64);
          bool c1 = bdn > v;
          bool c2 = bd > v;
          float nb  = c1 ? bdn  : (c2 ? v  : bd);
          int   nbi = c1 ? bin_ : (c2 ? vi : bi);
          bd = (lane < 16) ? nb  : -1e30f;
          bi = (lane < 16) ? nbi : bi;
          r = __shfl(bd, 0, 64);
        }
      }
    }
    if (lane < 16) knn[(size_t)gq * KNN_K + lane] = bi;
  }
}

// -------- K3: grouped linear (gather + GEMM) -------------------------------
__global__ __launch_bounds__(256) void k_gemm(const float* __restrict__ feat,
    const float* __restrict__ xyz, const float* __restrict__ new_xyz,
    const int* __restrict__ knn, const float* __restrict__ W,
    float* __restrict__ part_sum, float* __restrict__ part_sq,
    float* __restrict__ hmax_buf, float* __restrict__ hmin_buf,
    const float* __restrict__ scale, const float* __restrict__ bias,
    float* __restrict__ out, int mode) {
  __shared__ float sg[16][132];
  const int d = threadIdx.x;
  float w[132];
#pragma unroll
  for (int c = 0; c < 132; ++c) {
    if (c < 128)      w[c] = W[(size_t)(3 + c) * COUT + d];
    else if (c < 131) w[c] = W[(size_t)(c - 128) * COUT + d];
    else              w[c] = 0.0f;
  }
  float psum = 0.0f, psq = 0.0f;
  float sc = 0.0f, bb = 0.0f;
  if (mode == 1) { sc = scale[d]; bb = bias[d]; }
#pragma unroll 1
  for (int i = 0; i < GEMM_QPB; ++i) {
    const int gq = blockIdx.x * GEMM_QPB + i;
    const int b = gq >> 11;
    {
      const int row = d >> 4, sub = d & 15;
      const int nidx = knn[(size_t)gq * KNN_K + row];
      const float* frow = feat + ((size_t)b * NPTS + nidx) * CIN;
      const float4 a0 = *(const float4*)(frow + sub * 8);
      const float4 a1 = *(const float4*)(frow + sub * 8 + 4);
      *(float4*)&sg[row][sub * 8]     = a0;
      *(float4*)&sg[row][sub * 8 + 4] = a1;
      if (sub == 0) {
        const float gx = xyz[((size_t)b * NPTS + nidx) * 3 + 0];
        const float gy = xyz[((size_t)b * NPTS + nidx) * 3 + 1];
        const float gz = xyz[((size_t)b * NPTS + nidx) * 3 + 2];
        const float qx = new_xyz[(size_t)gq * 3 + 0];
        const float qy = new_xyz[(size_t)gq * 3 + 1];
        const float qz = new_xyz[(size_t)gq * 3 + 2];
        *(float4*)&sg[row][128] = make_float4(gx - qx, gy - qy, gz - qz, 0.0f);
      }
    }
    __syncthreads();
    float hmax = -1e30f, hmin = 1e30f;
#pragma unroll 1
    for (int k = 0; k < 16; ++k) {
      float a0 = 0.f, a1 = 0.f, a2 = 0.f, a3 = 0.f;
#pragma unroll
      for (int c4 = 0; c4 < 33; ++c4) {
        float4 g = *(const float4*)&sg[k][c4 * 4];
        a0 = fmaf(g.x, w[c4 * 4 + 0], a0);
        a1 = fmaf(g.y, w[c4 * 4 + 1], a1);
        a2 = fmaf(g.z, w[c4 * 4 + 2], a2);
        a3 = fmaf(g.w, w[c4 * 4 + 3], a3);
      }
      float h = (a0 + a1) + (a2 + a3);
      if (mode == 0) { psum += h; psq = fmaf(h, h, psq); }
      hmax = fmaxf(hmax, h); hmin = fminf(hmin, h);
    }
    if (mode == 0) {
      if (hmax_buf) {
        hmax_buf[(size_t)gq * COUT + d] = hmax;
        hmin_buf[(size_t)gq * COUT + d] = hmin;
      }
    } else {
      float hsel = (sc >= 0.0f) ? hmax : hmin;
      float o = fmaxf(fmaf(sc, hsel, bb), 0.0f);
      out[(size_t)gq * COUT + d] = o;
    }
    __syncthreads();
  }
  if (mode == 0) {
    part_sum[(size_t)blockIdx.x * COUT + d] = psum;
    part_sq [(size_t)blockIdx.x * COUT + d] = psq;
  }
}

// ---------------- K4: fold partials into BN scale/bias -----------------------
__global__ __launch_bounds__(256) void k_stats(const float* __restrict__ part_sum,
    const float* __restrict__ part_sq, const float* __restrict__ gamma,
    const float* __restrict__ beta, float* __restrict__ scale,
    float* __restrict__ bias) {
  const int d = threadIdx.x;
  float s = 0.0f, q = 0.0f;
  for (int bl = 0; bl < GEMM_BLOCKS; ++bl) {
    s += part_sum[(size_t)bl * COUT + d];
    q += part_sq[(size_t)bl * COUT + d];
  }
  const float inv = 1.0f / 262144.0f;
  float mean = s * inv;
  float var = q * inv - mean * mean;
  float scv = gamma[d] / sqrtf(var + 1e-5f);
  scale[d] = scv;
  bias[d] = beta[d] - mean * scv;
}

// ---------------- K5: elementwise finalize from hmax/hmin --------------------
__global__ __launch_bounds__(256) void k_final(const float* __restrict__ hmax_buf,
    const float* __restrict__ hmin_buf, const float* __restrict__ scale,
    const float* __restrict__ bias, float* __restrict__ out) {
  const int e4 = (blockIdx.x * 256 + threadIdx.x) * 4;
  const int d0 = e4 & (COUT - 1);
  const float4 hx = *(const float4*)&hmax_buf[e4];
  const float4 hn = *(const float4*)&hmin_buf[e4];
  const float4 sc = *(const float4*)&scale[d0];
  const float4 bb = *(const float4*)&bias[d0];
  float4 o;
  o.x = fmaxf(fmaf(sc.x, (sc.x >= 0.f) ? hx.x : hn.x, bb.x), 0.f);
  o.y = fmaxf(fmaf(sc.y, (sc.y >= 0.f) ? hx.y : hn.y, bb.y), 0.f);
  o.z = fmaxf(fmaf(sc.z, (sc.z >= 0.f) ? hx.z : hn.z, bb.z), 0.f);
  o.w = fmaxf(fmaf(sc.w, (sc.w >= 0.f) ? hx.w : hn.w, bb.w), 0.f);
  *(float4*)&out[e4] = o;
}

extern "C" void kernel_launch(void* const* d_in, const int* in_sizes, int n_in,
                              void* d_out, int out_size, void* d_ws, size_t ws_size,
                              hipStream_t stream) {
  const float* xyz   = (const float*)d_in[0];
  const float* feat  = (const float*)d_in[1];
  const float* W     = (const float*)d_in[2];
  const float* gamma = (const float*)d_in[3];
  const float* beta  = (const float*)d_in[4];
  float* out_xyz = (float*)d_out;
  float* out_nf  = out_xyz + (size_t)NB * NP * 3;

  // workspace layout
  char* ws = (char*)d_ws;
  int*   knn   = (int*)ws;                                      // 1 MB
  float* srt_x = (float*)(ws + (1 << 20));                      // 256 KB each
  float* srt_y = srt_x + NB * NPTS;
  float* srt_z = srt_y + NB * NPTS;
  int*   srt_o = (int*)(srt_z + NB * NPTS);
  char*  ws2   = ws + (2 << 20);
  float* hmax_buf = (float*)ws2;                                // 16.78 MB
  float* hmin_buf = (float*)(ws2 + ((size_t)GQ_TOTAL * COUT * 4));
  float* part_sum = (float*)(ws2 + 2ull * GQ_TOTAL * COUT * 4);
  float* part_sq  = part_sum + GEMM_BLOCKS * COUT;
  float* scale    = part_sq + GEMM_BLOCKS * COUT;
  float* bias     = scale + COUT;
  const size_t need_fused = (2ull << 20) + 2ull * GQ_TOTAL * COUT * 4
                          + 2ull * GEMM_BLOCKS * COUT * 4 + 2 * COUT * 4 + 256;
  const bool fused = ws_size >= need_fused;

  hipLaunchKernelGGL(k_sort, dim3(NB), dim3(1024), 0, stream, xyz,
                     srt_x, srt_y, srt_z, srt_o);
  hipLaunchKernelGGL(k_fps, dim3(NB), dim3(1024), 0, stream, xyz,
                     srt_x, srt_y, srt_z, srt_o, out_xyz);
  hipLaunchKernelGGL(k_knn, dim3(256), dim3(256), 0, stream, xyz, out_xyz, knn);
  if (fused) {
    hipLaunchKernelGGL(k_gemm, dim3(GEMM_BLOCKS), dim3(256), 0, stream, feat, xyz,
                       out_xyz, knn, W, part_sum, part_sq, hmax_buf, hmin_buf,
                       (const float*)nullptr, (const float*)nullptr,
                       (float*)nullptr, 0);
    hipLaunchKernelGGL(k_stats, dim3(1), dim3(256), 0, stream, part_sum, part_sq,
                       gamma, beta, scale, bias);
    hipLaunchKernelGGL(k_final, dim3(GQ_TOTAL * COUT / 1024), dim3(256), 0, stream,
                       hmax_buf, hmin_buf, scale, bias, out_nf);
  } else {
    float* f_part_sum = (float*)ws2;
    float* f_part_sq  = f_part_sum + GEMM_BLOCKS * COUT;
    float* f_scale    = f_part_sq + GEMM_BLOCKS * COUT;
    float* f_bias     = f_scale + COUT;
    hipLaunchKernelGGL(k_gemm, dim3(GEMM_BLOCKS), dim3(256), 0, stream, feat, xyz,
                       out_xyz, knn, W, f_part_sum, f_part_sq,
                       (float*)nullptr, (float*)nullptr,
                       (const float*)nullptr, (const float*)nullptr,
                       (float*)nullptr, 0);
    hipLaunchKernelGGL(k_stats, dim3(1), dim3(256), 0, stream, f_part_sum,
                       f_part_sq, gamma, beta, f_scale, f_bias);
    hipLaunchKernelGGL(k_gemm, dim3(GEMM_BLOCKS), dim3(256), 0, stream, feat, xyz,
                       out_xyz, knn, W, (float*)nullptr, (float*)nullptr,
                       (float*)nullptr, (float*)nullptr, f_scale, f_bias,
                       out_nf, 1);
  }
}